// Round 1
// 935.677 us; speedup vs baseline: 1.2711x; 1.2711x over previous
//
#include <hip/hip_runtime.h>
#include <hip/hip_bf16.h>
#include <cstdint>
#include <cstddef>

// Problem: B=2048, C=8, D=2048. All per-channel GEMMs are 2048x2048x2048.
#define NN 2048
#define CCH 8

using f32x4  = __attribute__((ext_vector_type(4))) float;
using bf16x8 = __attribute__((ext_vector_type(8))) __bf16;

__device__ __forceinline__ unsigned short f2bf(float f) {
  union { __bf16 b; unsigned short u; } v; v.b = (__bf16)f; return v.u;
}

// async global->LDS, 16B per lane. LDS dest is wave-uniform base; HW scatters lane l to base + l*16.
__device__ __forceinline__ void async_load16(const void* gp, void* lp) {
  __builtin_amdgcn_global_load_lds(
      (__attribute__((address_space(1))) void*)(void*)gp,
      (__attribute__((address_space(3))) void*)lp, 16, 0, 0);
}

// ---------------------------------------------------------------------------
// Pack x[b][c][d] (f32) -> xb[c][b][d] (bf16)
// ---------------------------------------------------------------------------
__global__ __launch_bounds__(256) void cast_x(const float* __restrict__ x,
                                              unsigned short* __restrict__ xb) {
  const size_t i4 = ((size_t)blockIdx.x * 256 + threadIdx.x) * 4;
  const int    d  = (int)(i4 & (NN - 1));
  const size_t t  = i4 >> 11;
  const int    ch = (int)(t & (CCH - 1));
  const size_t b  = t >> 3;
  const float4 v  = *(const float4*)(x + i4);
  ushort4 o;
  o.x = f2bf(v.x); o.y = f2bf(v.y); o.z = f2bf(v.z); o.w = f2bf(v.w);
  *(ushort4*)&xb[((size_t)ch * NN + b) * NN + d] = o;
}

// ---------------------------------------------------------------------------
// W[c][d][o] (f32) -> Wt[c][o][d] (bf16), 32x32 LDS tile transpose.
// z in [0,16): z<8 -> Wq, else Wk; channel = z&7.
// ---------------------------------------------------------------------------
__global__ __launch_bounds__(256) void transpose_cast(const float* __restrict__ Wq,
                                                      const float* __restrict__ Wk,
                                                      unsigned short* __restrict__ Wqt,
                                                      unsigned short* __restrict__ Wkt) {
  const int z  = blockIdx.z;
  const int ch = z & 7;
  const float* src          = (z < 8 ? Wq : Wk) + (size_t)ch * NN * NN;
  unsigned short* dst       = (z < 8 ? Wqt : Wkt) + (size_t)ch * NN * NN;
  __shared__ float tile[32][33];
  const int o0 = blockIdx.x * 32;
  const int d0 = blockIdx.y * 32;
  const int tx = threadIdx.x, ty = threadIdx.y; // (32, 8)
#pragma unroll
  for (int k = 0; k < 4; ++k)
    tile[ty + 8 * k][tx] = src[(size_t)(d0 + ty + 8 * k) * NN + (o0 + tx)];
  __syncthreads();
#pragma unroll
  for (int k = 0; k < 4; ++k)
    dst[(size_t)(o0 + ty + 8 * k) * NN + (d0 + tx)] = f2bf(tile[tx][ty + 8 * k]);
}

// ---------------------------------------------------------------------------
// TN GEMM: C[m][n] = sum_k A[m][k] * B[n][k]  (A,B bf16 k-contiguous, fp32 acc)
// 256x256 tile, BK=64, 512 threads = 8 waves (2M x 4N), each wave 128x64 output.
// 8-phase schedule (guide §5 template): per phase {ds_read subtile | stage one
// half-tile via global_load_lds -> s_barrier -> 16 MFMA (setprio) -> s_barrier},
// counted s_waitcnt vmcnt(2) only at phases 4 and 8. LDS XOR-swizzle realized by
// pre-swizzled global source (linear gload_lds dest) + same XOR on ds_read.
//
// MODE 0 (QK):  v = acc + bias[m]; store bf16 C[m][n]; rowsum(v^2) -> accP[m]
// MODE 1 (EXP): v = exp(acc / max(sqrt(rowP[m]*colP[n]), 1e-12)); store bf16; rowsum(v) -> accP[m]
// MODE 2 (Z):   v = acc / colP[n]; store f32 to out[(m*CCH + c)*NN + n]
// ---------------------------------------------------------------------------
template <int MODE>
__global__ __launch_bounds__(512, 2) void gemm_tn(const unsigned short* __restrict__ A,
                                                  const unsigned short* __restrict__ B,
                                                  void* __restrict__ Cout,
                                                  const float* __restrict__ rowP,
                                                  const float* __restrict__ colP,
                                                  float* __restrict__ accP) {
  const int    c  = blockIdx.z;
  const size_t MS = (size_t)NN * NN;
  const unsigned short* Ac = A + (size_t)c * MS;
  const unsigned short* Bc = B + (size_t)c * MS;

  // 128 KiB total: As/Bs double-buffered 256x64 bf16 tiles. rsum aliases (epilogue only).
  __shared__ union __attribute__((aligned(16))) {
    struct { unsigned short As[2][256 * 64]; unsigned short Bs[2][256 * 64]; } t;
    float rsum[256];
  } sm;

  const int tid  = threadIdx.x;
  const int wave = tid >> 6;
  const int lane = tid & 63;
  const int wm   = wave >> 2;   // 0..1  (M wave-row)
  const int wn   = wave & 3;    // 0..3  (N wave-col)
  const int fr   = lane & 15;
  const int quad = lane >> 4;

  const int mBase = blockIdx.y * 256;
  const int nBase = blockIdx.x * 256;

  // staging geometry: wave w, inst s covers LDS rows [h*128 + s*64 + w*8, +8).
  // swizzle: LDS[row][chunk] holds global chunk (chunk ^ (row&7)); row&7 == r0&7.
  const int r0  = (wave << 3) + (lane >> 3);      // row within 64-row slab
  const int csw = (lane & 7) ^ (r0 & 7);          // pre-swizzled 16B chunk
  const unsigned short* gA = Ac + (size_t)(mBase + r0) * NN + csw * 8;
  const unsigned short* gB = Bc + (size_t)(nBase + r0) * NN + csw * 8;

  f32x4  acc[8][4] = {};
  bf16x8 af[4][2];
  bf16x8 bf0[2][2];
  bf16x8 bf1[2][2];

#define STAGE_A(buf, h, kt)                                                              \
  {                                                                                      \
    const unsigned short* _s = gA + (size_t)((h) * 128) * NN + (size_t)(kt) * 64;        \
    async_load16(_s,                   &sm.t.As[buf][((h) * 128 +      wave * 8) * 64]); \
    async_load16(_s + (size_t)64 * NN, &sm.t.As[buf][((h) * 128 + 64 + wave * 8) * 64]); \
  }
#define STAGE_B(buf, h, kt)                                                              \
  {                                                                                      \
    const unsigned short* _s = gB + (size_t)((h) * 128) * NN + (size_t)(kt) * 64;        \
    async_load16(_s,                   &sm.t.Bs[buf][((h) * 128 +      wave * 8) * 64]); \
    async_load16(_s + (size_t)64 * NN, &sm.t.Bs[buf][((h) * 128 + 64 + wave * 8) * 64]); \
  }
// A fragment reads for m-half h: rows wm*128 + h*64 + i*16 + fr, swizzled chunk.
#define LDA_(buf, h)                                                                      \
  _Pragma("unroll") for (int i = 0; i < 4; ++i)                                           \
  _Pragma("unroll") for (int kk = 0; kk < 2; ++kk)                                        \
    af[i][kk] = *(const bf16x8*)&sm.t.As[buf][(wm * 128 + (h) * 64 + i * 16 + fr) * 64 +  \
                                             (((kk << 2) | quad) ^ (fr & 7)) * 8];
#define LDB_(buf, g, arr)                                                                 \
  _Pragma("unroll") for (int j = 0; j < 2; ++j)                                           \
  _Pragma("unroll") for (int kk = 0; kk < 2; ++kk)                                        \
    arr[j][kk] = *(const bf16x8*)&sm.t.Bs[buf][(wn * 64 + (g) * 32 + j * 16 + fr) * 64 +  \
                                              (((kk << 2) | quad) ^ (fr & 7)) * 8];
#define MM_(h, g, arr)                                                                    \
  __builtin_amdgcn_s_setprio(1);                                                          \
  _Pragma("unroll") for (int i = 0; i < 4; ++i)                                           \
  _Pragma("unroll") for (int j = 0; j < 2; ++j) {                                         \
    acc[(h) * 4 + i][(g) * 2 + j] = __builtin_amdgcn_mfma_f32_16x16x32_bf16(              \
        af[i][0], arr[j][0], acc[(h) * 4 + i][(g) * 2 + j], 0, 0, 0);                     \
    acc[(h) * 4 + i][(g) * 2 + j] = __builtin_amdgcn_mfma_f32_16x16x32_bf16(              \
        af[i][1], arr[j][1], acc[(h) * 4 + i][(g) * 2 + j], 0, 0, 0);                     \
  }                                                                                       \
  __builtin_amdgcn_s_setprio(0);
#define FENCE_ asm volatile("" ::: "memory")
#define BAR_   { FENCE_; __builtin_amdgcn_s_barrier(); FENCE_; }
#define VM2_   asm volatile("s_waitcnt vmcnt(2)" ::: "memory")
#define VM0_   asm volatile("s_waitcnt vmcnt(0)" ::: "memory")

  // Prologue: K-tile 0 fully into buf0, K-tile 1 A-half0 into buf1; wait kt0 landed.
  STAGE_A(0, 0, 0); STAGE_A(0, 1, 0); STAGE_B(0, 0, 0); STAGE_B(0, 1, 0);
  STAGE_A(1, 0, 1);
  VM2_; BAR_;

  // Region lifetimes (verified): A-halves of a buf consumed end of P3/P7,
  // B-halves end of P2/P6. Stage one half-tile/phase; vmcnt(2) at P4/P8 keeps
  // only the just-issued half-tile in flight, guaranteeing everything a
  // subsequent phase reads has landed.
#pragma unroll 1
  for (int it = 0; it < 15; ++it) {
    const int ko = 2 * it + 1;   // odd K-tile -> buf1
    const int ke = 2 * it + 2;   // next even K-tile -> buf0
    // P1
    LDA_(0, 0); LDB_(0, 0, bf0); STAGE_A(1, 1, ko);
    BAR_; MM_(0, 0, bf0); BAR_;
    // P2
    LDB_(0, 1, bf1); STAGE_B(1, 0, ko);
    BAR_; MM_(0, 1, bf1); BAR_;
    // P3
    LDA_(0, 1); STAGE_B(1, 1, ko);
    BAR_; MM_(1, 0, bf0); BAR_;
    // P4
    STAGE_A(0, 0, ke);
    BAR_; MM_(1, 1, bf1); VM2_; BAR_;
    // P5
    LDA_(1, 0); LDB_(1, 0, bf0); STAGE_A(0, 1, ke);
    BAR_; MM_(0, 0, bf0); BAR_;
    // P6
    LDB_(1, 1, bf1); STAGE_B(0, 0, ke);
    BAR_; MM_(0, 1, bf1); BAR_;
    // P7
    LDA_(1, 1); STAGE_B(0, 1, ke);
    BAR_; MM_(1, 0, bf0); BAR_;
    // P8
    STAGE_A(1, 0, ko + 2);
    BAR_; MM_(1, 1, bf1); VM2_; BAR_;
  }
  // Peeled final iteration: kt30 in buf0, kt31 in buf1 (halves #1..#3 staged here).
  LDA_(0, 0); LDB_(0, 0, bf0); STAGE_A(1, 1, 31);
  BAR_; MM_(0, 0, bf0); BAR_;
  LDB_(0, 1, bf1); STAGE_B(1, 0, 31);
  BAR_; MM_(0, 1, bf1); BAR_;
  LDA_(0, 1); STAGE_B(1, 1, 31);
  BAR_; MM_(1, 0, bf0); BAR_;
  BAR_; MM_(1, 1, bf1); VM0_; BAR_;
  LDA_(1, 0); LDB_(1, 0, bf0);
  BAR_; MM_(0, 0, bf0); BAR_;
  LDB_(1, 1, bf1);
  BAR_; MM_(0, 1, bf1); BAR_;
  LDA_(1, 1);
  BAR_; MM_(1, 0, bf0); BAR_;
  MM_(1, 1, bf1);

  FENCE_;
  __syncthreads();   // all LDS reads done before rsum aliases the tiles

  if constexpr (MODE == 0) {
    if (tid < 256) sm.rsum[tid] = 0.0f;
    __syncthreads();
    unsigned short* Co = (unsigned short*)Cout + (size_t)c * MS;
    const float* biasC = rowP + c * NN;
    float* dsq         = accP + c * NN;
#pragma unroll
    for (int i = 0; i < 8; ++i) {
#pragma unroll
      for (int r = 0; r < 4; ++r) {
        const int lrow   = wm * 128 + i * 16 + quad * 4 + r;
        const int row    = mBase + lrow;
        const float bias = biasC[row];
        float ss = 0.0f;
#pragma unroll
        for (int j = 0; j < 4; ++j) {
          const int col = nBase + wn * 64 + j * 16 + fr;
          float v = acc[i][j][r] + bias;
          Co[(size_t)row * NN + col] = f2bf(v);
          ss += v * v;
        }
#pragma unroll
        for (int m = 8; m >= 1; m >>= 1) ss += __shfl_xor(ss, m, 64);
        if (fr == 0) atomicAdd(&sm.rsum[lrow], ss);
      }
    }
    __syncthreads();
    if (tid < 256) atomicAdd(&dsq[mBase + tid], sm.rsum[tid]);
  } else if constexpr (MODE == 1) {
    if (tid < 256) sm.rsum[tid] = 0.0f;
    __syncthreads();
    unsigned short* Co = (unsigned short*)Cout + (size_t)c * MS;
    const float* dk2C  = rowP + c * NN;  // row index m
    const float* dq2C  = colP + c * NN;  // col index n
    float* csum        = accP + c * NN;
    float dq[4];
#pragma unroll
    for (int j = 0; j < 4; ++j) dq[j] = dq2C[nBase + wn * 64 + j * 16 + fr];
#pragma unroll
    for (int i = 0; i < 8; ++i) {
#pragma unroll
      for (int r = 0; r < 4; ++r) {
        const int lrow = wm * 128 + i * 16 + quad * 4 + r;
        const int row  = mBase + lrow;
        const float dk = dk2C[row];
        float es = 0.0f;
#pragma unroll
        for (int j = 0; j < 4; ++j) {
          const int col = nBase + wn * 64 + j * 16 + fr;
          const float denom = fmaxf(sqrtf(dk * dq[j]), 1e-12f);
          const float e = __expf(acc[i][j][r] / denom);  // |Y|<=1: no max-sub needed
          Co[(size_t)row * NN + col] = f2bf(e);
          es += e;
        }
#pragma unroll
        for (int m = 8; m >= 1; m >>= 1) es += __shfl_xor(es, m, 64);
        if (fr == 0) atomicAdd(&sm.rsum[lrow], es);
      }
    }
    __syncthreads();
    if (tid < 256) atomicAdd(&csum[mBase + tid], sm.rsum[tid]);
  } else {
    float* Co        = (float*)Cout;   // [B][C][D]
    const float* csC = colP + c * NN;  // colsum indexed by n = o
    float rcs[4];
#pragma unroll
    for (int j = 0; j < 4; ++j) rcs[j] = 1.0f / csC[nBase + wn * 64 + j * 16 + fr];
#pragma unroll
    for (int i = 0; i < 8; ++i)
#pragma unroll
      for (int r = 0; r < 4; ++r) {
        const int row = mBase + wm * 128 + i * 16 + quad * 4 + r;  // b
#pragma unroll
        for (int j = 0; j < 4; ++j) {
          const int col = nBase + wn * 64 + j * 16 + fr;  // o
          Co[((size_t)row * CCH + c) * NN + col] = acc[i][j][r] * rcs[j];
        }
      }
  }
#undef STAGE_A
#undef STAGE_B
#undef LDA_
#undef LDB_
#undef MM_
#undef FENCE_
#undef BAR_
#undef VM2_
#undef VM0_
}

// ---------------------------------------------------------------------------
extern "C" void kernel_launch(void* const* d_in, const int* in_sizes, int n_in,
                              void* d_out, int out_size, void* d_ws, size_t ws_size,
                              hipStream_t stream) {
  const float* x   = (const float*)d_in[0];
  const float* Wq  = (const float*)d_in[1];
  const float* Wq0 = (const float*)d_in[2];
  const float* Wk  = (const float*)d_in[3];
  const float* Wk0 = (const float*)d_in[4];

  const size_t S = (size_t)NN * NN * CCH;  // elements per big buffer (bf16 -> 2*S bytes)
  char* ws = (char*)d_ws;
  unsigned short* xb  = (unsigned short*)(ws);
  unsigned short* Wqt = (unsigned short*)(ws + 2 * S);
  unsigned short* Wkt = (unsigned short*)(ws + 4 * S);
  unsigned short* Qt  = (unsigned short*)(ws + 6 * S);
  unsigned short* Kt  = (unsigned short*)(ws + 8 * S);
  unsigned short* Et  = Wqt;  // Wqt dead after GEMM1q -> reuse for exp(Y)
  float* stats = (float*)(ws + 10 * S);
  float* dq2   = stats;                 // [C][D] sum_b Q^2
  float* dk2   = stats + CCH * NN;      // [C][D] sum_b K^2
  float* csum  = stats + 2 * CCH * NN;  // [C][D] softmax denominators

  hipMemsetAsync(stats, 0, 3 * CCH * NN * sizeof(float), stream);
  cast_x<<<32768, 256, 0, stream>>>(x, xb);
  transpose_cast<<<dim3(64, 64, 16), dim3(32, 8), 0, stream>>>(Wq, Wk, Wqt, Wkt);

  dim3 gg(8, 8, 8);
  // Qt[o][b] = sum_d Wqt[o][d]*xb[b][d] + q0[o];  dq2[o] += row sums of squares
  gemm_tn<0><<<gg, 512, 0, stream>>>(Wqt, xb, Qt, Wq0, nullptr, dq2);
  gemm_tn<0><<<gg, 512, 0, stream>>>(Wkt, xb, Kt, Wk0, nullptr, dk2);
  // Et[o][p] = exp( (sum_b Kt[o][b]*Qt[p][b]) / max(sqrt(dk2[o]*dq2[p]),eps) ); csum += rowsum
  gemm_tn<1><<<gg, 512, 0, stream>>>(Kt, Qt, Et, dk2, dq2, csum);
  // Z[b][c][o] = (sum_p xb[b][p]*Et[o][p]) / csum[o]
  gemm_tn<2><<<gg, 512, 0, stream>>>(xb, Et, d_out, nullptr, csum, nullptr);
}

// Round 2
// 911.311 us; speedup vs baseline: 1.3050x; 1.0267x over previous
//
#include <hip/hip_runtime.h>
#include <hip/hip_bf16.h>
#include <cstdint>
#include <cstddef>

// Problem: B=2048, C=8, D=2048. All per-channel GEMMs are 2048x2048x2048.
#define NN 2048
#define CCH 8

using f32x4  = __attribute__((ext_vector_type(4))) float;
using bf16x8 = __attribute__((ext_vector_type(8))) __bf16;

__device__ __forceinline__ unsigned short f2bf(float f) {
  union { __bf16 b; unsigned short u; } v; v.b = (__bf16)f; return v.u;
}

// async global->LDS, 16B per lane. LDS dest is wave-uniform base; HW scatters lane l to base + l*16.
__device__ __forceinline__ void async_load16(const void* gp, void* lp) {
  __builtin_amdgcn_global_load_lds(
      (__attribute__((address_space(1))) void*)(void*)gp,
      (__attribute__((address_space(3))) void*)lp, 16, 0, 0);
}

// ---------------------------------------------------------------------------
// Pack x[b][c][d] (f32) -> xb[c][b][d] (bf16)
// ---------------------------------------------------------------------------
__global__ __launch_bounds__(256) void cast_x(const float* __restrict__ x,
                                              unsigned short* __restrict__ xb) {
  const size_t i4 = ((size_t)blockIdx.x * 256 + threadIdx.x) * 4;
  const int    d  = (int)(i4 & (NN - 1));
  const size_t t  = i4 >> 11;
  const int    ch = (int)(t & (CCH - 1));
  const size_t b  = t >> 3;
  const float4 v  = *(const float4*)(x + i4);
  ushort4 o;
  o.x = f2bf(v.x); o.y = f2bf(v.y); o.z = f2bf(v.z); o.w = f2bf(v.w);
  *(ushort4*)&xb[((size_t)ch * NN + b) * NN + d] = o;
}

// ---------------------------------------------------------------------------
// W[c][d][o] (f32) -> Wt[c][o][d] (bf16), 64x64 LDS tile transpose.
// float4 global loads, ushort4 global stores. z in [0,16): z<8 -> Wq, else Wk.
// ---------------------------------------------------------------------------
__global__ __launch_bounds__(256) void transpose_cast(const float* __restrict__ Wq,
                                                      const float* __restrict__ Wk,
                                                      unsigned short* __restrict__ Wqt,
                                                      unsigned short* __restrict__ Wkt) {
  const int z  = blockIdx.z;
  const int ch = z & 7;
  const float* src    = (z < 8 ? Wq : Wk) + (size_t)ch * NN * NN;
  unsigned short* dst = (z < 8 ? Wqt : Wkt) + (size_t)ch * NN * NN;
  __shared__ float tile[64][65];   // stride 65: column reads are 2-way max (free)
  const int o0 = blockIdx.x * 64;
  const int d0 = blockIdx.y * 64;
  const int t  = threadIdx.x;
  const int tx = t & 15, ty = t >> 4;
#pragma unroll
  for (int k = 0; k < 4; ++k) {
    const float4 v = *(const float4*)&src[(size_t)(d0 + ty + 16 * k) * NN + (o0 + tx * 4)];
    tile[ty + 16 * k][tx * 4 + 0] = v.x;
    tile[ty + 16 * k][tx * 4 + 1] = v.y;
    tile[ty + 16 * k][tx * 4 + 2] = v.z;
    tile[ty + 16 * k][tx * 4 + 3] = v.w;
  }
  __syncthreads();
  const int ud = t & 15, uo = t >> 4;
#pragma unroll
  for (int k = 0; k < 4; ++k) {
    const int o = uo + 16 * k;
    ushort4 w;
    w.x = f2bf(tile[ud * 4 + 0][o]);
    w.y = f2bf(tile[ud * 4 + 1][o]);
    w.z = f2bf(tile[ud * 4 + 2][o]);
    w.w = f2bf(tile[ud * 4 + 3][o]);
    *(ushort4*)&dst[(size_t)(o0 + o) * NN + d0 + ud * 4] = w;
  }
}

// ---------------------------------------------------------------------------
// TN GEMM: C[m][n] = sum_k A[m][k] * B[n][k]  (A,B bf16 k-contiguous, fp32 acc)
// 256x256 tile, BK=64, 512 threads = 8 waves (2M x 4N), each wave 128x64 output.
// 8-phase schedule, counted vmcnt(2) at P4/P8 only. Staging front-loaded
// (P1: 2 half-tiles, P2: 1, P4: 1; symmetric P5/P6/P8) so the last half-tile
// a wait depends on was issued >=2.5 phases earlier (latency slack).
// 1-D grid + bijective XCD swizzle: 64 consecutive dispatch ids -> one XCD
// -> one channel per XCD (A/B panels L2-resident per XCD).
//
// MODE 0 (QK):  v = acc + bias[m]; store bf16 C[m][n]; rowsum(v^2) -> accP[m]
// MODE 1 (EXP): v = exp(acc / max(sqrt(rowP[m]*colP[n]), 1e-12)); store bf16; rowsum(v) -> accP[m]
// MODE 2 (Z):   v = acc / colP[n]; store f32 to out[(m*CCH + c)*NN + n]
// ---------------------------------------------------------------------------
template <int MODE>
__global__ __launch_bounds__(512, 2) void gemm_tn(const unsigned short* __restrict__ A,
                                                  const unsigned short* __restrict__ B,
                                                  void* __restrict__ Cout,
                                                  const float* __restrict__ rowP,
                                                  const float* __restrict__ colP,
                                                  float* __restrict__ accP) {
  // XCD swizzle: hw round-robins dispatch id over 8 XCDs; remap so XCD k gets
  // the 64 blocks of channel k (grid 8x8 tiles per channel). 512 % 8 == 0 -> bijective.
  const int wg  = blockIdx.x;                 // 0..511
  const int lin = ((wg & 7) << 6) | (wg >> 3);
  const int c   = lin >> 6;                   // channel == XCD id
  const int by  = (lin >> 3) & 7;
  const int bx  = lin & 7;

  const size_t MS = (size_t)NN * NN;
  const unsigned short* Ac = A + (size_t)c * MS;
  const unsigned short* Bc = B + (size_t)c * MS;

  // 128 KiB total: As/Bs double-buffered 256x64 bf16 tiles. rsum aliases (epilogue only).
  __shared__ union __attribute__((aligned(16))) {
    struct { unsigned short As[2][256 * 64]; unsigned short Bs[2][256 * 64]; } t;
    float rsum[256];
  } sm;

  const int tid  = threadIdx.x;
  const int wave = tid >> 6;
  const int lane = tid & 63;
  const int wm   = wave >> 2;   // 0..1  (M wave-row)
  const int wn   = wave & 3;    // 0..3  (N wave-col)
  const int fr   = lane & 15;
  const int quad = lane >> 4;

  const int mBase = by * 256;
  const int nBase = bx * 256;

  // staging geometry: wave w, inst s covers LDS rows [h*128 + s*64 + w*8, +8).
  // swizzle: LDS[row][chunk] holds global chunk (chunk ^ (row&7)); row&7 == r0&7.
  const int r0  = (wave << 3) + (lane >> 3);      // row within 64-row slab
  const int csw = (lane & 7) ^ (r0 & 7);          // pre-swizzled 16B chunk
  const unsigned short* gA = Ac + (size_t)(mBase + r0) * NN + csw * 8;
  const unsigned short* gB = Bc + (size_t)(nBase + r0) * NN + csw * 8;

  f32x4  acc[8][4] = {};
  bf16x8 af[4][2];
  bf16x8 bf0[2][2];
  bf16x8 bf1[2][2];

#define STAGE_A(buf, h, kt)                                                              \
  {                                                                                      \
    const unsigned short* _s = gA + (size_t)((h) * 128) * NN + (size_t)(kt) * 64;        \
    async_load16(_s,                   &sm.t.As[buf][((h) * 128 +      wave * 8) * 64]); \
    async_load16(_s + (size_t)64 * NN, &sm.t.As[buf][((h) * 128 + 64 + wave * 8) * 64]); \
  }
#define STAGE_B(buf, h, kt)                                                              \
  {                                                                                      \
    const unsigned short* _s = gB + (size_t)((h) * 128) * NN + (size_t)(kt) * 64;        \
    async_load16(_s,                   &sm.t.Bs[buf][((h) * 128 +      wave * 8) * 64]); \
    async_load16(_s + (size_t)64 * NN, &sm.t.Bs[buf][((h) * 128 + 64 + wave * 8) * 64]); \
  }
// A fragment reads for m-half h: rows wm*128 + h*64 + i*16 + fr, swizzled chunk.
#define LDA_(buf, h)                                                                      \
  _Pragma("unroll") for (int i = 0; i < 4; ++i)                                           \
  _Pragma("unroll") for (int kk = 0; kk < 2; ++kk)                                        \
    af[i][kk] = *(const bf16x8*)&sm.t.As[buf][(wm * 128 + (h) * 64 + i * 16 + fr) * 64 +  \
                                             (((kk << 2) | quad) ^ (fr & 7)) * 8];
#define LDB_(buf, g, arr)                                                                 \
  _Pragma("unroll") for (int j = 0; j < 2; ++j)                                           \
  _Pragma("unroll") for (int kk = 0; kk < 2; ++kk)                                        \
    arr[j][kk] = *(const bf16x8*)&sm.t.Bs[buf][(wn * 64 + (g) * 32 + j * 16 + fr) * 64 +  \
                                              (((kk << 2) | quad) ^ (fr & 7)) * 8];
#define MM_(h, g, arr)                                                                    \
  __builtin_amdgcn_s_setprio(1);                                                          \
  _Pragma("unroll") for (int i = 0; i < 4; ++i)                                           \
  _Pragma("unroll") for (int j = 0; j < 2; ++j) {                                         \
    acc[(h) * 4 + i][(g) * 2 + j] = __builtin_amdgcn_mfma_f32_16x16x32_bf16(              \
        af[i][0], arr[j][0], acc[(h) * 4 + i][(g) * 2 + j], 0, 0, 0);                     \
    acc[(h) * 4 + i][(g) * 2 + j] = __builtin_amdgcn_mfma_f32_16x16x32_bf16(              \
        af[i][1], arr[j][1], acc[(h) * 4 + i][(g) * 2 + j], 0, 0, 0);                     \
  }                                                                                       \
  __builtin_amdgcn_s_setprio(0);
#define FENCE_ asm volatile("" ::: "memory")
#define BAR_   { FENCE_; __builtin_amdgcn_s_barrier(); FENCE_; }
#define VM2_   asm volatile("s_waitcnt vmcnt(2)" ::: "memory")
#define VM0_   asm volatile("s_waitcnt vmcnt(0)" ::: "memory")

  // Prologue: K-tile 0 fully into buf0, K-tile 1 A-half0 into buf1; wait kt0 landed.
  STAGE_A(0, 0, 0); STAGE_A(0, 1, 0); STAGE_B(0, 0, 0); STAGE_B(0, 1, 0);
  STAGE_A(1, 0, 1);
  VM2_; BAR_;

  // Region lifetimes (verified): each staged region's last reader is >=2 barriers
  // before the stage issue. Waits: P4's vmcnt(2) needs everything through P2's
  // issues landed (2.5-phase slack); P8's needs through P6's (2.5-phase slack).
#pragma unroll 1
  for (int it = 0; it < 15; ++it) {
    const int ko = 2 * it + 1;   // odd K-tile -> buf1
    const int ke = 2 * it + 2;   // next even K-tile -> buf0
    // P1
    LDA_(0, 0); LDB_(0, 0, bf0); STAGE_A(1, 1, ko); STAGE_B(1, 0, ko);
    BAR_; MM_(0, 0, bf0); BAR_;
    // P2
    LDB_(0, 1, bf1); STAGE_B(1, 1, ko);
    BAR_; MM_(0, 1, bf1); BAR_;
    // P3
    LDA_(0, 1);
    BAR_; MM_(1, 0, bf0); BAR_;
    // P4
    STAGE_A(0, 0, ke);
    BAR_; MM_(1, 1, bf1); VM2_; BAR_;
    // P5
    LDA_(1, 0); LDB_(1, 0, bf0); STAGE_A(0, 1, ke); STAGE_B(0, 0, ke);
    BAR_; MM_(0, 0, bf0); BAR_;
    // P6
    LDB_(1, 1, bf1); STAGE_B(0, 1, ke);
    BAR_; MM_(0, 1, bf1); BAR_;
    // P7
    LDA_(1, 1);
    BAR_; MM_(1, 0, bf0); BAR_;
    // P8
    STAGE_A(1, 0, ko + 2);
    BAR_; MM_(1, 1, bf1); VM2_; BAR_;
  }
  // Peeled final iteration: kt30 in buf0, kt31 in buf1 (halves #1..#3 staged here).
  LDA_(0, 0); LDB_(0, 0, bf0); STAGE_A(1, 1, 31); STAGE_B(1, 0, 31);
  BAR_; MM_(0, 0, bf0); BAR_;
  LDB_(0, 1, bf1); STAGE_B(1, 1, 31);
  BAR_; MM_(0, 1, bf1); BAR_;
  LDA_(0, 1);
  BAR_; MM_(1, 0, bf0); BAR_;
  BAR_; MM_(1, 1, bf1); VM0_; BAR_;
  LDA_(1, 0); LDB_(1, 0, bf0);
  BAR_; MM_(0, 0, bf0); BAR_;
  LDB_(1, 1, bf1);
  BAR_; MM_(0, 1, bf1); BAR_;
  LDA_(1, 1);
  BAR_; MM_(1, 0, bf0); BAR_;
  MM_(1, 1, bf1);

  FENCE_;
  __syncthreads();   // all LDS reads done before rsum aliases the tiles

  if constexpr (MODE == 0) {
    if (tid < 256) sm.rsum[tid] = 0.0f;
    __syncthreads();
    unsigned short* Co = (unsigned short*)Cout + (size_t)c * MS;
    const float* biasC = rowP + c * NN;
    float* dsq         = accP + c * NN;
#pragma unroll
    for (int i = 0; i < 8; ++i) {
#pragma unroll
      for (int r = 0; r < 4; ++r) {
        const int lrow   = wm * 128 + i * 16 + quad * 4 + r;
        const int row    = mBase + lrow;
        const float bias = biasC[row];
        float ss = 0.0f;
#pragma unroll
        for (int j = 0; j < 4; ++j) {
          const int col = nBase + wn * 64 + j * 16 + fr;
          float v = acc[i][j][r] + bias;
          Co[(size_t)row * NN + col] = f2bf(v);
          ss += v * v;
        }
#pragma unroll
        for (int m = 8; m >= 1; m >>= 1) ss += __shfl_xor(ss, m, 64);
        if (fr == 0) atomicAdd(&sm.rsum[lrow], ss);
      }
    }
    __syncthreads();
    if (tid < 256) atomicAdd(&dsq[mBase + tid], sm.rsum[tid]);
  } else if constexpr (MODE == 1) {
    if (tid < 256) sm.rsum[tid] = 0.0f;
    __syncthreads();
    unsigned short* Co = (unsigned short*)Cout + (size_t)c * MS;
    const float* dk2C  = rowP + c * NN;  // row index m
    const float* dq2C  = colP + c * NN;  // col index n
    float* csum        = accP + c * NN;
    float dq[4];
#pragma unroll
    for (int j = 0; j < 4; ++j) dq[j] = dq2C[nBase + wn * 64 + j * 16 + fr];
#pragma unroll
    for (int i = 0; i < 8; ++i) {
#pragma unroll
      for (int r = 0; r < 4; ++r) {
        const int lrow = wm * 128 + i * 16 + quad * 4 + r;
        const int row  = mBase + lrow;
        const float dk = dk2C[row];
        float es = 0.0f;
#pragma unroll
        for (int j = 0; j < 4; ++j) {
          const int col = nBase + wn * 64 + j * 16 + fr;
          const float denom = fmaxf(sqrtf(dk * dq[j]), 1e-12f);
          const float e = __expf(acc[i][j][r] / denom);  // |Y|<=1: no max-sub needed
          Co[(size_t)row * NN + col] = f2bf(e);
          es += e;
        }
#pragma unroll
        for (int m = 8; m >= 1; m >>= 1) es += __shfl_xor(es, m, 64);
        if (fr == 0) atomicAdd(&sm.rsum[lrow], es);
      }
    }
    __syncthreads();
    if (tid < 256) atomicAdd(&csum[mBase + tid], sm.rsum[tid]);
  } else {
    float* Co        = (float*)Cout;   // [B][C][D]
    const float* csC = colP + c * NN;  // colsum indexed by n = o
    float rcs[4];
#pragma unroll
    for (int j = 0; j < 4; ++j) rcs[j] = 1.0f / csC[nBase + wn * 64 + j * 16 + fr];
#pragma unroll
    for (int i = 0; i < 8; ++i)
#pragma unroll
      for (int r = 0; r < 4; ++r) {
        const int row = mBase + wm * 128 + i * 16 + quad * 4 + r;  // b
#pragma unroll
        for (int j = 0; j < 4; ++j) {
          const int col = nBase + wn * 64 + j * 16 + fr;  // o
          Co[((size_t)row * CCH + c) * NN + col] = acc[i][j][r] * rcs[j];
        }
      }
  }
#undef STAGE_A
#undef STAGE_B
#undef LDA_
#undef LDB_
#undef MM_
#undef FENCE_
#undef BAR_
#undef VM2_
#undef VM0_
}

// ---------------------------------------------------------------------------
extern "C" void kernel_launch(void* const* d_in, const int* in_sizes, int n_in,
                              void* d_out, int out_size, void* d_ws, size_t ws_size,
                              hipStream_t stream) {
  const float* x   = (const float*)d_in[0];
  const float* Wq  = (const float*)d_in[1];
  const float* Wq0 = (const float*)d_in[2];
  const float* Wk  = (const float*)d_in[3];
  const float* Wk0 = (const float*)d_in[4];

  const size_t S = (size_t)NN * NN * CCH;  // elements per big buffer (bf16 -> 2*S bytes)
  char* ws = (char*)d_ws;
  unsigned short* xb  = (unsigned short*)(ws);
  unsigned short* Wqt = (unsigned short*)(ws + 2 * S);
  unsigned short* Wkt = (unsigned short*)(ws + 4 * S);
  unsigned short* Qt  = (unsigned short*)(ws + 6 * S);
  unsigned short* Kt  = (unsigned short*)(ws + 8 * S);
  unsigned short* Et  = Wqt;  // Wqt dead after GEMM1q -> reuse for exp(Y)
  float* stats = (float*)(ws + 10 * S);
  float* dq2   = stats;                 // [C][D] sum_b Q^2
  float* dk2   = stats + CCH * NN;      // [C][D] sum_b K^2
  float* csum  = stats + 2 * CCH * NN;  // [C][D] softmax denominators

  hipMemsetAsync(stats, 0, 3 * CCH * NN * sizeof(float), stream);
  cast_x<<<32768, 256, 0, stream>>>(x, xb);
  transpose_cast<<<dim3(32, 32, 16), 256, 0, stream>>>(Wq, Wk, Wqt, Wkt);

  // Qt[o][b] = sum_d Wqt[o][d]*xb[b][d] + q0[o];  dq2[o] += row sums of squares
  gemm_tn<0><<<512, 512, 0, stream>>>(Wqt, xb, Qt, Wq0, nullptr, dq2);
  gemm_tn<0><<<512, 512, 0, stream>>>(Wkt, xb, Kt, Wk0, nullptr, dk2);
  // Et[o][p] = exp( (sum_b Kt[o][b]*Qt[p][b]) / max(sqrt(dk2[o]*dq2[p]),eps) ); csum += rowsum
  gemm_tn<1><<<512, 512, 0, stream>>>(Kt, Qt, Et, dk2, dq2, csum);
  // Z[b][c][o] = (sum_p xb[b][p]*Et[o][p]) / csum[o]
  gemm_tn<2><<<512, 512, 0, stream>>>(xb, Et, d_out, nullptr, csum, nullptr);
}

// Round 3
// 910.042 us; speedup vs baseline: 1.3069x; 1.0014x over previous
//
#include <hip/hip_runtime.h>
#include <hip/hip_bf16.h>
#include <cstdint>
#include <cstddef>

// Problem: B=2048, C=8, D=2048. All per-channel GEMMs are 2048x2048x2048.
#define NN 2048
#define CCH 8

using f32x4  = __attribute__((ext_vector_type(4))) float;
using bf16x8 = __attribute__((ext_vector_type(8))) __bf16;

__device__ __forceinline__ unsigned short f2bf(float f) {
  union { __bf16 b; unsigned short u; } v; v.b = (__bf16)f; return v.u;
}

// async global->LDS, 16B per lane. LDS dest is wave-uniform base; HW scatters lane l to base + l*16.
__device__ __forceinline__ void async_load16(const void* gp, void* lp) {
  __builtin_amdgcn_global_load_lds(
      (__attribute__((address_space(1))) void*)(void*)gp,
      (__attribute__((address_space(3))) void*)lp, 16, 0, 0);
}

// ---------------------------------------------------------------------------
// Pack x[b][c][d] (f32) -> xb[c][b][d] (bf16)
// ---------------------------------------------------------------------------
__global__ __launch_bounds__(256) void cast_x(const float* __restrict__ x,
                                              unsigned short* __restrict__ xb) {
  const size_t i4 = ((size_t)blockIdx.x * 256 + threadIdx.x) * 4;
  const int    d  = (int)(i4 & (NN - 1));
  const size_t t  = i4 >> 11;
  const int    ch = (int)(t & (CCH - 1));
  const size_t b  = t >> 3;
  const float4 v  = *(const float4*)(x + i4);
  ushort4 o;
  o.x = f2bf(v.x); o.y = f2bf(v.y); o.z = f2bf(v.z); o.w = f2bf(v.w);
  *(ushort4*)&xb[((size_t)ch * NN + b) * NN + d] = o;
}

// ---------------------------------------------------------------------------
// W[c][d][o] (f32) -> Wt[c][o][d] (bf16), 64x64 LDS tile transpose.
// float4 global loads, ushort4 global stores. z in [0,16): z<8 -> Wq, else Wk.
// ---------------------------------------------------------------------------
__global__ __launch_bounds__(256) void transpose_cast(const float* __restrict__ Wq,
                                                      const float* __restrict__ Wk,
                                                      unsigned short* __restrict__ Wqt,
                                                      unsigned short* __restrict__ Wkt) {
  const int z  = blockIdx.z;
  const int ch = z & 7;
  const float* src    = (z < 8 ? Wq : Wk) + (size_t)ch * NN * NN;
  unsigned short* dst = (z < 8 ? Wqt : Wkt) + (size_t)ch * NN * NN;
  __shared__ float tile[64][65];   // stride 65: column reads are 2-way max (free)
  const int o0 = blockIdx.x * 64;
  const int d0 = blockIdx.y * 64;
  const int t  = threadIdx.x;
  const int tx = t & 15, ty = t >> 4;
#pragma unroll
  for (int k = 0; k < 4; ++k) {
    const float4 v = *(const float4*)&src[(size_t)(d0 + ty + 16 * k) * NN + (o0 + tx * 4)];
    tile[ty + 16 * k][tx * 4 + 0] = v.x;
    tile[ty + 16 * k][tx * 4 + 1] = v.y;
    tile[ty + 16 * k][tx * 4 + 2] = v.z;
    tile[ty + 16 * k][tx * 4 + 3] = v.w;
  }
  __syncthreads();
  const int ud = t & 15, uo = t >> 4;
#pragma unroll
  for (int k = 0; k < 4; ++k) {
    const int o = uo + 16 * k;
    ushort4 w;
    w.x = f2bf(tile[ud * 4 + 0][o]);
    w.y = f2bf(tile[ud * 4 + 1][o]);
    w.z = f2bf(tile[ud * 4 + 2][o]);
    w.w = f2bf(tile[ud * 4 + 3][o]);
    *(ushort4*)&dst[(size_t)(o0 + o) * NN + d0 + ud * 4] = w;
  }
}

// ---------------------------------------------------------------------------
// TN GEMM: C[m][n] = sum_k A[m][k] * B[n][k]  (A,B bf16 k-contiguous, fp32 acc)
// 256x256 tile, BK=64, 512 threads = 8 waves (2M x 4N), each wave 128x64 output.
// 8-phase schedule: ONE half-tile staged per staging phase (m196: fine
// interleave is load-bearing), counted vmcnt(2) at P4/P8 only.
// 1-D grid + bijective XCD swizzle: 64 consecutive lin ids -> one XCD
// -> one channel per XCD (A/B panels L2-resident; staging = L2 hits ~200cy,
// well inside the ~620cy one-phase slack).
//
// MODE 0 (QK):  v = acc + bias[m]; store bf16 C[m][n]; rowsum(v^2) -> accP[m]
// MODE 1 (EXP): v = exp(acc / max(sqrt(rowP[m]*colP[n]), 1e-12)); store bf16; rowsum(v) -> accP[m]
// MODE 2 (Z):   v = acc / colP[n]; store f32 to out[(m*CCH + c)*NN + n]
// ---------------------------------------------------------------------------
template <int MODE>
__global__ __launch_bounds__(512, 2) void gemm_tn(const unsigned short* __restrict__ A,
                                                  const unsigned short* __restrict__ B,
                                                  void* __restrict__ Cout,
                                                  const float* __restrict__ rowP,
                                                  const float* __restrict__ colP,
                                                  float* __restrict__ accP) {
  // XCD swizzle: hw round-robins dispatch id over 8 XCDs; remap so XCD k gets
  // the 64 blocks of channel k (grid 8x8 tiles per channel). 512 % 8 == 0 -> bijective.
  const int wg  = blockIdx.x;                 // 0..511
  const int lin = ((wg & 7) << 6) | (wg >> 3);
  const int c   = lin >> 6;                   // channel == XCD id
  const int by  = (lin >> 3) & 7;
  const int bx  = lin & 7;

  const size_t MS = (size_t)NN * NN;
  const unsigned short* Ac = A + (size_t)c * MS;
  const unsigned short* Bc = B + (size_t)c * MS;

  // 128 KiB total: As/Bs double-buffered 256x64 bf16 tiles. rsum aliases (epilogue only).
  __shared__ union __attribute__((aligned(16))) {
    struct { unsigned short As[2][256 * 64]; unsigned short Bs[2][256 * 64]; } t;
    float rsum[256];
  } sm;

  const int tid  = threadIdx.x;
  const int wave = tid >> 6;
  const int lane = tid & 63;
  const int wm   = wave >> 2;   // 0..1  (M wave-row)
  const int wn   = wave & 3;    // 0..3  (N wave-col)
  const int fr   = lane & 15;
  const int quad = lane >> 4;

  const int mBase = by * 256;
  const int nBase = bx * 256;

  // staging geometry: wave w, inst s covers LDS rows [h*128 + s*64 + w*8, +8).
  // swizzle: LDS[row][chunk] holds global chunk (chunk ^ (row&7)); row&7 == r0&7.
  const int r0  = (wave << 3) + (lane >> 3);      // row within 64-row slab
  const int csw = (lane & 7) ^ (r0 & 7);          // pre-swizzled 16B chunk
  const unsigned short* gA = Ac + (size_t)(mBase + r0) * NN + csw * 8;
  const unsigned short* gB = Bc + (size_t)(nBase + r0) * NN + csw * 8;

  f32x4  acc[8][4] = {};
  bf16x8 af[4][2];
  bf16x8 bf0[2][2];
  bf16x8 bf1[2][2];

#define STAGE_A(buf, h, kt)                                                              \
  {                                                                                      \
    const unsigned short* _s = gA + (size_t)((h) * 128) * NN + (size_t)(kt) * 64;        \
    async_load16(_s,                   &sm.t.As[buf][((h) * 128 +      wave * 8) * 64]); \
    async_load16(_s + (size_t)64 * NN, &sm.t.As[buf][((h) * 128 + 64 + wave * 8) * 64]); \
  }
#define STAGE_B(buf, h, kt)                                                              \
  {                                                                                      \
    const unsigned short* _s = gB + (size_t)((h) * 128) * NN + (size_t)(kt) * 64;        \
    async_load16(_s,                   &sm.t.Bs[buf][((h) * 128 +      wave * 8) * 64]); \
    async_load16(_s + (size_t)64 * NN, &sm.t.Bs[buf][((h) * 128 + 64 + wave * 8) * 64]); \
  }
// A fragment reads for m-half h: rows wm*128 + h*64 + i*16 + fr, swizzled chunk.
#define LDA_(buf, h)                                                                      \
  _Pragma("unroll") for (int i = 0; i < 4; ++i)                                           \
  _Pragma("unroll") for (int kk = 0; kk < 2; ++kk)                                        \
    af[i][kk] = *(const bf16x8*)&sm.t.As[buf][(wm * 128 + (h) * 64 + i * 16 + fr) * 64 +  \
                                             (((kk << 2) | quad) ^ (fr & 7)) * 8];
#define LDB_(buf, g, arr)                                                                 \
  _Pragma("unroll") for (int j = 0; j < 2; ++j)                                           \
  _Pragma("unroll") for (int kk = 0; kk < 2; ++kk)                                        \
    arr[j][kk] = *(const bf16x8*)&sm.t.Bs[buf][(wn * 64 + (g) * 32 + j * 16 + fr) * 64 +  \
                                              (((kk << 2) | quad) ^ (fr & 7)) * 8];
#define MM_(h, g, arr)                                                                    \
  __builtin_amdgcn_s_setprio(1);                                                          \
  _Pragma("unroll") for (int i = 0; i < 4; ++i)                                           \
  _Pragma("unroll") for (int j = 0; j < 2; ++j) {                                         \
    acc[(h) * 4 + i][(g) * 2 + j] = __builtin_amdgcn_mfma_f32_16x16x32_bf16(              \
        af[i][0], arr[j][0], acc[(h) * 4 + i][(g) * 2 + j], 0, 0, 0);                     \
    acc[(h) * 4 + i][(g) * 2 + j] = __builtin_amdgcn_mfma_f32_16x16x32_bf16(              \
        af[i][1], arr[j][1], acc[(h) * 4 + i][(g) * 2 + j], 0, 0, 0);                     \
  }                                                                                       \
  __builtin_amdgcn_s_setprio(0);
#define FENCE_ asm volatile("" ::: "memory")
#define BAR_   { FENCE_; __builtin_amdgcn_s_barrier(); FENCE_; }
#define VM2_   asm volatile("s_waitcnt vmcnt(2)" ::: "memory")
#define VM0_   asm volatile("s_waitcnt vmcnt(0)" ::: "memory")

  // Prologue: K-tile 0 fully into buf0, K-tile 1 A-half0 into buf1; wait kt0 landed.
  STAGE_A(0, 0, 0); STAGE_A(0, 1, 0); STAGE_B(0, 0, 0); STAGE_B(0, 1, 0);
  STAGE_A(1, 0, 1);
  VM2_; BAR_;

  // Region lifetimes (verified): A-halves of a buf consumed end of P3/P7,
  // B-halves end of P2/P6. Stage one half-tile/phase; vmcnt(2) at P4/P8 keeps
  // only the just-issued half-tile in flight, guaranteeing everything a
  // subsequent phase reads has landed.
#pragma unroll 1
  for (int it = 0; it < 15; ++it) {
    const int ko = 2 * it + 1;   // odd K-tile -> buf1
    const int ke = 2 * it + 2;   // next even K-tile -> buf0
    // P1
    LDA_(0, 0); LDB_(0, 0, bf0); STAGE_A(1, 1, ko);
    BAR_; MM_(0, 0, bf0); BAR_;
    // P2
    LDB_(0, 1, bf1); STAGE_B(1, 0, ko);
    BAR_; MM_(0, 1, bf1); BAR_;
    // P3
    LDA_(0, 1); STAGE_B(1, 1, ko);
    BAR_; MM_(1, 0, bf0); BAR_;
    // P4
    STAGE_A(0, 0, ke);
    BAR_; MM_(1, 1, bf1); VM2_; BAR_;
    // P5
    LDA_(1, 0); LDB_(1, 0, bf0); STAGE_A(0, 1, ke);
    BAR_; MM_(0, 0, bf0); BAR_;
    // P6
    LDB_(1, 1, bf1); STAGE_B(0, 0, ke);
    BAR_; MM_(0, 1, bf1); BAR_;
    // P7
    LDA_(1, 1); STAGE_B(0, 1, ke);
    BAR_; MM_(1, 0, bf0); BAR_;
    // P8
    STAGE_A(1, 0, ko + 2);
    BAR_; MM_(1, 1, bf1); VM2_; BAR_;
  }
  // Peeled final iteration: kt30 in buf0, kt31 in buf1 (halves #1..#3 staged here).
  LDA_(0, 0); LDB_(0, 0, bf0); STAGE_A(1, 1, 31);
  BAR_; MM_(0, 0, bf0); BAR_;
  LDB_(0, 1, bf1); STAGE_B(1, 0, 31);
  BAR_; MM_(0, 1, bf1); BAR_;
  LDA_(0, 1); STAGE_B(1, 1, 31);
  BAR_; MM_(1, 0, bf0); BAR_;
  BAR_; MM_(1, 1, bf1); VM0_; BAR_;
  LDA_(1, 0); LDB_(1, 0, bf0);
  BAR_; MM_(0, 0, bf0); BAR_;
  LDB_(1, 1, bf1);
  BAR_; MM_(0, 1, bf1); BAR_;
  LDA_(1, 1);
  BAR_; MM_(1, 0, bf0); BAR_;
  MM_(1, 1, bf1);

  FENCE_;
  __syncthreads();   // all LDS reads done before rsum aliases the tiles

  if constexpr (MODE == 0) {
    if (tid < 256) sm.rsum[tid] = 0.0f;
    __syncthreads();
    unsigned short* Co = (unsigned short*)Cout + (size_t)c * MS;
    const float* biasC = rowP + c * NN;
    float* dsq         = accP + c * NN;
#pragma unroll
    for (int i = 0; i < 8; ++i) {
#pragma unroll
      for (int r = 0; r < 4; ++r) {
        const int lrow   = wm * 128 + i * 16 + quad * 4 + r;
        const int row    = mBase + lrow;
        const float bias = biasC[row];
        float ss = 0.0f;
#pragma unroll
        for (int j = 0; j < 4; ++j) {
          const int col = nBase + wn * 64 + j * 16 + fr;
          float v = acc[i][j][r] + bias;
          Co[(size_t)row * NN + col] = f2bf(v);
          ss += v * v;
        }
#pragma unroll
        for (int m = 8; m >= 1; m >>= 1) ss += __shfl_xor(ss, m, 64);
        if (fr == 0) atomicAdd(&sm.rsum[lrow], ss);
      }
    }
    __syncthreads();
    if (tid < 256) atomicAdd(&dsq[mBase + tid], sm.rsum[tid]);
  } else if constexpr (MODE == 1) {
    if (tid < 256) sm.rsum[tid] = 0.0f;
    __syncthreads();
    unsigned short* Co = (unsigned short*)Cout + (size_t)c * MS;
    const float* dk2C  = rowP + c * NN;  // row index m
    const float* dq2C  = colP + c * NN;  // col index n
    float* csum        = accP + c * NN;
    float dq[4];
#pragma unroll
    for (int j = 0; j < 4; ++j) dq[j] = dq2C[nBase + wn * 64 + j * 16 + fr];
#pragma unroll
    for (int i = 0; i < 8; ++i) {
#pragma unroll
      for (int r = 0; r < 4; ++r) {
        const int lrow = wm * 128 + i * 16 + quad * 4 + r;
        const int row  = mBase + lrow;
        const float dk = dk2C[row];
        float es = 0.0f;
#pragma unroll
        for (int j = 0; j < 4; ++j) {
          const int col = nBase + wn * 64 + j * 16 + fr;
          const float denom = fmaxf(sqrtf(dk * dq[j]), 1e-12f);
          const float e = __expf(acc[i][j][r] / denom);  // |Y|<=1: no max-sub needed
          Co[(size_t)row * NN + col] = f2bf(e);
          es += e;
        }
#pragma unroll
        for (int m = 8; m >= 1; m >>= 1) es += __shfl_xor(es, m, 64);
        if (fr == 0) atomicAdd(&sm.rsum[lrow], es);
      }
    }
    __syncthreads();
    if (tid < 256) atomicAdd(&csum[mBase + tid], sm.rsum[tid]);
  } else {
    float* Co        = (float*)Cout;   // [B][C][D]
    const float* csC = colP + c * NN;  // colsum indexed by n = o
    float rcs[4];
#pragma unroll
    for (int j = 0; j < 4; ++j) rcs[j] = 1.0f / csC[nBase + wn * 64 + j * 16 + fr];
#pragma unroll
    for (int i = 0; i < 8; ++i)
#pragma unroll
      for (int r = 0; r < 4; ++r) {
        const int row = mBase + wm * 128 + i * 16 + quad * 4 + r;  // b
#pragma unroll
        for (int j = 0; j < 4; ++j) {
          const int col = nBase + wn * 64 + j * 16 + fr;  // o
          Co[((size_t)row * CCH + c) * NN + col] = acc[i][j][r] * rcs[j];
        }
      }
  }
#undef STAGE_A
#undef STAGE_B
#undef LDA_
#undef LDB_
#undef MM_
#undef FENCE_
#undef BAR_
#undef VM2_
#undef VM0_
}

// ---------------------------------------------------------------------------
extern "C" void kernel_launch(void* const* d_in, const int* in_sizes, int n_in,
                              void* d_out, int out_size, void* d_ws, size_t ws_size,
                              hipStream_t stream) {
  const float* x   = (const float*)d_in[0];
  const float* Wq  = (const float*)d_in[1];
  const float* Wq0 = (const float*)d_in[2];
  const float* Wk  = (const float*)d_in[3];
  const float* Wk0 = (const float*)d_in[4];

  const size_t S = (size_t)NN * NN * CCH;  // elements per big buffer (bf16 -> 2*S bytes)
  char* ws = (char*)d_ws;
  unsigned short* xb  = (unsigned short*)(ws);
  unsigned short* Wqt = (unsigned short*)(ws + 2 * S);
  unsigned short* Wkt = (unsigned short*)(ws + 4 * S);
  unsigned short* Qt  = (unsigned short*)(ws + 6 * S);
  unsigned short* Kt  = (unsigned short*)(ws + 8 * S);
  unsigned short* Et  = Wqt;  // Wqt dead after GEMM1q -> reuse for exp(Y)
  float* stats = (float*)(ws + 10 * S);
  float* dq2   = stats;                 // [C][D] sum_b Q^2
  float* dk2   = stats + CCH * NN;      // [C][D] sum_b K^2
  float* csum  = stats + 2 * CCH * NN;  // [C][D] softmax denominators

  hipMemsetAsync(stats, 0, 3 * CCH * NN * sizeof(float), stream);
  cast_x<<<32768, 256, 0, stream>>>(x, xb);
  transpose_cast<<<dim3(32, 32, 16), 256, 0, stream>>>(Wq, Wk, Wqt, Wkt);

  // Qt[o][b] = sum_d Wqt[o][d]*xb[b][d] + q0[o];  dq2[o] += row sums of squares
  gemm_tn<0><<<512, 512, 0, stream>>>(Wqt, xb, Qt, Wq0, nullptr, dq2);
  gemm_tn<0><<<512, 512, 0, stream>>>(Wkt, xb, Kt, Wk0, nullptr, dk2);
  // Et[o][p] = exp( (sum_b Kt[o][b]*Qt[p][b]) / max(sqrt(dk2[o]*dq2[p]),eps) ); csum += rowsum
  gemm_tn<1><<<512, 512, 0, stream>>>(Kt, Qt, Et, dk2, dq2, csum);
  // Z[b][c][o] = (sum_p xb[b][p]*Et[o][p]) / csum[o]
  gemm_tn<2><<<512, 512, 0, stream>>>(xb, Et, d_out, nullptr, csum, nullptr);
}